// Round 1
// baseline (2533.255 us; speedup 1.0000x reference)
//
#include <hip/hip_runtime.h>

#define B_   512
#define H_   1024
#define G4   4096
#define OUT_ 512
#define T_   128
#define APAD 72   // padded LDS row stride in f16 (144B, 16B-aligned, bank-friendly)

typedef _Float16 h8  __attribute__((ext_vector_type(8)));
typedef _Float16 h4  __attribute__((ext_vector_type(4)));
typedef float    f32x4 __attribute__((ext_vector_type(4)));

#define MFMA16(a,b,c) __builtin_amdgcn_mfma_f32_16x16x32_f16(a,b,c,0,0,0)

__device__ __forceinline__ float sigmoidf_(float x) { return 1.f / (1.f + __expf(-x)); }

// ---------------------------------------------------------------------------
// setup: f32->f16 weight conversion, b_sum = b_ih+b_hh, zero c blob and h0
// ---------------------------------------------------------------------------
__global__ __launch_bounds__(256) void setup_kernel(
    const float* __restrict__ Wih, const float* __restrict__ Whh,
    const float* __restrict__ bih, const float* __restrict__ bhh,
    const float* __restrict__ Wlin,
    _Float16* __restrict__ Wih16, _Float16* __restrict__ Whh16,
    _Float16* __restrict__ Wlin16, float* __restrict__ bsum,
    float* __restrict__ cblob, _Float16* __restrict__ h0) {
  int i = blockIdx.x * blockDim.x + threadIdx.x;
  int stride = gridDim.x * blockDim.x;
  const f32x4* wih4 = (const f32x4*)Wih;
  const f32x4* whh4 = (const f32x4*)Whh;
  h4* wih16 = (h4*)Wih16;
  h4* whh16 = (h4*)Whh16;
  f32x4 z = {};
  for (int idx = i; idx < (G4 * H_) / 4; idx += stride) {  // 1048576
    f32x4 a = wih4[idx], b = whh4[idx];
    h4 va, vb;
#pragma unroll
    for (int r = 0; r < 4; ++r) { va[r] = (_Float16)a[r]; vb[r] = (_Float16)b[r]; }
    wih16[idx] = va; whh16[idx] = vb;
    if (idx < (OUT_ * H_) / 4) {                  // 131072
      f32x4 c = ((const f32x4*)Wlin)[idx];
      h4 vc;
#pragma unroll
      for (int r = 0; r < 4; ++r) vc[r] = (_Float16)c[r];
      ((h4*)Wlin16)[idx] = vc;
      ((f32x4*)cblob)[idx] = z;                   // c blob = B_*H_ f32 = 131072 f32x4
    }
    if (idx < (B_ * H_ * 2) / 16)                 // h0: 1MB f16 = 65536 f32x4
      ((f32x4*)h0)[idx] = z;
    if (idx < G4 / 4)                             // 1024
      ((f32x4*)bsum)[idx] = ((const f32x4*)bih)[idx] + ((const f32x4*)bhh)[idx];
  }
}

// ---------------------------------------------------------------------------
// projection tile: out[t][m0:m0+32][n0:n0+64] = h @ W_lin^T + b_lin
// pid in [0,128): 16 m-tiles x 8 n-tiles. 256 threads, wave w owns 16 out-cols.
// ---------------------------------------------------------------------------
__device__ __forceinline__ void proj_tile(int pid,
                                          const _Float16* __restrict__ h,
                                          const _Float16* __restrict__ Wlin16,
                                          const float* __restrict__ blin,
                                          float* __restrict__ outp,
                                          _Float16* smem) {
  int m0 = (pid >> 3) * 32, n0 = (pid & 7) * 64;
  int tid = threadIdx.x, w = tid >> 6, lane = tid & 63;
  _Float16* A_s = smem;               // [32][APAD]
  _Float16* B_s = smem + 32 * APAD;   // [64][APAD]
  f32x4 acc[2] = {};
  int fr_row = lane & 15, fr_k = (lane >> 4) * 8;
  int ar = tid >> 3, ac = (tid & 7) * 8;     // A: 32 rows x 8 chunks of 8 f16
  int br = tid >> 2, bq = (tid & 3) * 16;    // B: 64 rows x 4 chunks of 16 f16

  for (int kt = 0; kt < 16; ++kt) {
    int k0 = kt * 64;
    *(h8*)&A_s[ar * APAD + ac] = *(const h8*)(h + (size_t)(m0 + ar) * H_ + k0 + ac);
    const _Float16* bsrc = Wlin16 + (size_t)(n0 + br) * H_ + k0 + bq;
    *(h8*)&B_s[br * APAD + bq]     = *(const h8*)bsrc;
    *(h8*)&B_s[br * APAD + bq + 8] = *(const h8*)(bsrc + 8);
    __syncthreads();
#pragma unroll
    for (int s2 = 0; s2 < 2; ++s2) {
      int ks = s2 * 32 + fr_k;
      h8 a0 = *(const h8*)&A_s[fr_row * APAD + ks];
      h8 a1 = *(const h8*)&A_s[(16 + fr_row) * APAD + ks];
      h8 b  = *(const h8*)&B_s[(w * 16 + fr_row) * APAD + ks];
      acc[0] = MFMA16(a0, b, acc[0]);
      acc[1] = MFMA16(a1, b, acc[1]);
    }
    __syncthreads();
  }
  // repack to f32 LDS tile [32][16] per wave, then coalesced stores
  float* fr = (float*)smem + w * 512;
  float bl = blin[n0 + w * 16 + fr_row];
#pragma unroll
  for (int mf = 0; mf < 2; ++mf)
#pragma unroll
    for (int r = 0; r < 4; ++r)
      fr[((lane >> 4) * 4 + r + mf * 16) * 16 + fr_row] = acc[mf][r] + bl;
  __syncthreads();
  int row = lane >> 2, q = (lane & 3) * 4;
#pragma unroll
  for (int p = 0; p < 2; ++p) {
    f32x4 v = *(f32x4*)&fr[(row + p * 16) * 16 + q];
    *(f32x4*)(outp + (size_t)(m0 + row + p * 16) * OUT_ + n0 + w * 16 + q) = v;
  }
}

// ---------------------------------------------------------------------------
// Gates GEMM (+ LSTM epilogue) / x_proj GEMM.
// Gate block tile: BM=64 batch x BJ=32 hidden, all 4 gate panels (eff N=128).
// 256 blocks (exact CU count), 256 threads (4 waves: 2 m-halves x 2 j-halves).
// IS_XPROJ=1: A = C (f32, cvt on the fly), writes x_proj blob (+b_sum).
// IS_XPROJ=0: A = h_in (f16); epilogue does LSTM cell; blockIdx>=256 does proj.
// ---------------------------------------------------------------------------
template <int IS_XPROJ>
__global__ __launch_bounds__(256) void gates_step_kernel(
    const void* __restrict__ Ag, const _Float16* __restrict__ Wg,
    const float* __restrict__ bsum, float* __restrict__ xblob,
    float* __restrict__ cblob, _Float16* __restrict__ hout,
    const _Float16* __restrict__ Wlin16, const float* __restrict__ blin,
    float* __restrict__ outp) {
  __shared__ __align__(16) _Float16 smem[64 * APAD + 128 * APAD];  // 27.6 KB

  if (!IS_XPROJ && blockIdx.x >= 256) {
    proj_tile(blockIdx.x - 256, (const _Float16*)Ag, Wlin16, blin, outp, smem);
    return;
  }

  int blk = blockIdx.x;
  // XCD swizzle: all 8 m-blocks of a j-panel land on one XCD -> W panel L2-hot
  int xcd = blk & 7, kq = blk >> 3;
  int j_idx = xcd * 4 + (kq & 3), m_idx = kq >> 2;
  int m0 = m_idx * 64, j0 = j_idx * 32;
  int tid = threadIdx.x, w = tid >> 6, lane = tid & 63;
  int mhalf = w >> 1, jhalf = w & 1;
  _Float16* A_s = smem;              // [64][APAD]
  _Float16* B_s = smem + 64 * APAD;  // [4*32][APAD]
  f32x4 acc[4][2] = {};
  int fr_row = lane & 15, fr_k = (lane >> 4) * 8;
  int ar = tid >> 2, ac = (tid & 3) * 16;          // A: 64 rows x 4 chunks of 16
  int r128 = tid >> 1, bg = r128 >> 5, brr = r128 & 31, bh = (tid & 1) * 32;
  const _Float16* Brow = Wg + (size_t)(bg * H_ + j0 + brr) * H_ + bh;

  for (int kt = 0; kt < 16; ++kt) {
    int k0 = kt * 64;
    if (IS_XPROJ) {
      const float* Af = (const float*)Ag;
      const f32x4* p = (const f32x4*)(Af + (size_t)(m0 + ar) * H_ + k0 + ac);
      f32x4 v0 = p[0], v1 = p[1], v2 = p[2], v3 = p[3];
      h8 hv0, hv1;
#pragma unroll
      for (int r = 0; r < 4; ++r) {
        hv0[r] = (_Float16)v0[r]; hv0[4 + r] = (_Float16)v1[r];
        hv1[r] = (_Float16)v2[r]; hv1[4 + r] = (_Float16)v3[r];
      }
      *(h8*)&A_s[ar * APAD + ac] = hv0;
      *(h8*)&A_s[ar * APAD + ac + 8] = hv1;
    } else {
      const _Float16* Ah = (const _Float16*)Ag;
      const h8* p = (const h8*)(Ah + (size_t)(m0 + ar) * H_ + k0 + ac);
      *(h8*)&A_s[ar * APAD + ac] = p[0];
      *(h8*)&A_s[ar * APAD + ac + 8] = p[1];
    }
    {
      const h8* src = (const h8*)(Brow + k0);
      _Float16* dst = &B_s[(bg * 32 + brr) * APAD + bh];
#pragma unroll
      for (int q = 0; q < 4; ++q) *(h8*)&dst[q * 8] = src[q];
    }
    __syncthreads();
#pragma unroll
    for (int s2 = 0; s2 < 2; ++s2) {
      int ks = s2 * 32 + fr_k;
      h8 a0 = *(const h8*)&A_s[(mhalf * 32 + fr_row) * APAD + ks];
      h8 a1 = *(const h8*)&A_s[(mhalf * 32 + 16 + fr_row) * APAD + ks];
#pragma unroll
      for (int g = 0; g < 4; ++g) {
        h8 b = *(const h8*)&B_s[(g * 32 + jhalf * 16 + fr_row) * APAD + ks];
        acc[g][0] = MFMA16(a0, b, acc[g][0]);
        acc[g][1] = MFMA16(a1, b, acc[g][1]);
      }
    }
    __syncthreads();
  }

  if (IS_XPROJ) {
    f32x4* xb = (f32x4*)xblob;
#pragma unroll
    for (int g = 0; g < 4; ++g) {
      float bs = bsum[g * H_ + j0 + jhalf * 16 + fr_row];
#pragma unroll
      for (int mf = 0; mf < 2; ++mf) {
        f32x4 v = acc[g][mf];
        v += bs;
        xb[(size_t)(blk * 32 + w * 8 + g * 2 + mf) * 64 + lane] = v;
      }
    }
  } else {
    f32x4* xb = (f32x4*)xblob;
    f32x4* cb = (f32x4*)cblob;
    _Float16* hr = smem + w * 512;   // per-wave repack region (inside A_s, loop done)
#pragma unroll
    for (int mf = 0; mf < 2; ++mf) {
      f32x4 xi = xb[(size_t)(blk * 32 + w * 8 + 0 + mf) * 64 + lane];
      f32x4 xf = xb[(size_t)(blk * 32 + w * 8 + 2 + mf) * 64 + lane];
      f32x4 xg = xb[(size_t)(blk * 32 + w * 8 + 4 + mf) * 64 + lane];
      f32x4 xo = xb[(size_t)(blk * 32 + w * 8 + 6 + mf) * 64 + lane];
      f32x4 cv = cb[(size_t)(blk * 8 + w * 2 + mf) * 64 + lane];
      f32x4 cn, hn;
#pragma unroll
      for (int r = 0; r < 4; ++r) {
        float iv = sigmoidf_(acc[0][mf][r] + xi[r]);
        float fv = sigmoidf_(acc[1][mf][r] + xf[r]);
        float gv = tanhf(acc[2][mf][r] + xg[r]);
        float ov = sigmoidf_(acc[3][mf][r] + xo[r]);
        float cc = fv * cv[r] + iv * gv;
        cn[r] = cc;
        hn[r] = ov * tanhf(cc);
      }
      cb[(size_t)(blk * 8 + w * 2 + mf) * 64 + lane] = cn;
#pragma unroll
      for (int r = 0; r < 4; ++r)
        hr[((lane >> 4) * 4 + r + mf * 16) * 16 + fr_row] = (_Float16)hn[r];
    }
    __syncthreads();
    int row = lane >> 1, hb2 = (lane & 1) * 8;
    h8 hv = *(const h8*)&hr[row * 16 + hb2];
    *(h8*)(hout + (size_t)(m0 + mhalf * 32 + row) * H_ + j0 + jhalf * 16 + hb2) = hv;
  }
}

__global__ __launch_bounds__(256) void proj_kernel(const _Float16* __restrict__ h,
                                                   const _Float16* __restrict__ Wlin16,
                                                   const float* __restrict__ blin,
                                                   float* __restrict__ outp) {
  __shared__ __align__(16) _Float16 smem[64 * APAD + 128 * APAD];
  proj_tile(blockIdx.x, h, Wlin16, blin, outp, smem);
}

// ---------------------------------------------------------------------------
extern "C" void kernel_launch(void* const* d_in, const int* in_sizes, int n_in,
                              void* d_out, int out_size, void* d_ws, size_t ws_size,
                              hipStream_t stream) {
  const float* C    = (const float*)d_in[0];
  const float* Wih  = (const float*)d_in[3];
  const float* Whh  = (const float*)d_in[4];
  const float* bih  = (const float*)d_in[5];
  const float* bhh  = (const float*)d_in[6];
  const float* Wlin = (const float*)d_in[7];
  const float* blin = (const float*)d_in[8];
  float* out = (float*)d_out;

  char* ws = (char*)d_ws;
  size_t off = 0;
  auto alloc = [&](size_t bytes) {
    void* p = ws + off;
    off = (off + bytes + 255) & ~(size_t)255;
    return p;
  };
  _Float16* Wih16  = (_Float16*)alloc((size_t)G4 * H_ * 2);
  _Float16* Whh16  = (_Float16*)alloc((size_t)G4 * H_ * 2);
  _Float16* Wlin16 = (_Float16*)alloc((size_t)OUT_ * H_ * 2);
  float*    bsum   = (float*)alloc((size_t)G4 * 4);
  float*    xblob  = (float*)alloc((size_t)B_ * G4 * 4);
  float*    cblob  = (float*)alloc((size_t)B_ * H_ * 4);
  _Float16* hb0    = (_Float16*)alloc((size_t)B_ * H_ * 2);
  _Float16* hb1    = (_Float16*)alloc((size_t)B_ * H_ * 2);
  if (off > ws_size) return;  // workspace too small (not expected: ~29 MB)

  hipLaunchKernelGGL(setup_kernel, dim3(4096), dim3(256), 0, stream,
                     Wih, Whh, bih, bhh, Wlin, Wih16, Whh16, Wlin16, bsum, cblob, hb0);

  hipLaunchKernelGGL((gates_step_kernel<1>), dim3(256), dim3(256), 0, stream,
                     (const void*)C, Wih16, bsum, xblob, (float*)nullptr,
                     (_Float16*)nullptr, (const _Float16*)nullptr,
                     (const float*)nullptr, (float*)nullptr);

  _Float16* hb[2] = {hb0, hb1};
  for (int s = 1; s <= T_; ++s) {
    const _Float16* hin = hb[(s - 1) & 1];
    _Float16* ho = hb[s & 1];
    int grid = (s >= 2) ? 384 : 256;
    float* outp = (s >= 2) ? (out + (size_t)(s - 2) * B_ * OUT_) : out;
    hipLaunchKernelGGL((gates_step_kernel<0>), dim3(grid), dim3(256), 0, stream,
                       (const void*)hin, Whh16, bsum, xblob, cblob, ho, Wlin16, blin, outp);
  }
  // out[127] from h_128 (lives in hb[0] since 128 is even)
  hipLaunchKernelGGL(proj_kernel, dim3(128), dim3(256), 0, stream,
                     hb[0], Wlin16, blin, out + (size_t)(T_ - 1) * B_ * OUT_);
}